// Round 14
// baseline (199.259 us; speedup 1.0000x reference)
//
#include <hip/hip_runtime.h>
#include <math.h>

typedef unsigned char u8;
typedef unsigned short u16;
typedef unsigned int u32;
typedef __attribute__((ext_vector_type(8))) short bf16x8;
typedef __attribute__((ext_vector_type(4))) float f32x4;

// d_out float offsets (outputs concatenated flat)
#define O1 16777216   // encoding_indices [32768]
#define O2 16809984   // v scalar
#define O3 16809985   // loss_key_energy_descent scalar
#define O4 16809986   // key_energy_mat [32768]
#define O5 16842754   // e_normal_mat [32768]
#define O6 16875522   // e_abnormal_mat [32768]

// ws byte offsets (all writes stay below 15099904 = proven footprint)
#define W_COLSQ 0           // 1025 f
#define W_MINV  4352        // 32768*16 f
#define W_MINI  2101504     // 32768*16 i
#define W_SF    4198656     // 32768*17 f
#define W_SL    6426880     // 32768*16 f
#define W_BITS  8524032     // 32768*128 bytes
#define W_MIDX  12718336    // 32768 i
#define W_ENC   12849408    // 32768 i
#define W_V     12980480    // 1 i
#define W_P5    12980736    // 128 f partials for k5
#define W_EH    13000704    // emb_hi PERMUTED [16 t][16 cbg][4 n][64 lane] x 16B = 1MB
#define W_EL    14050304    // emb_lo PERMUTED, same layout

__device__ __forceinline__ u32 cvt_pk(float lo, float hi) {   // D.l=bf16(lo) D.h=bf16(hi), RNE
  u32 r;
  asm volatile("v_cvt_pk_bf16_f32 %0, %1, %2" : "=v"(r) : "v"(lo), "v"(hi));
  return r;
}
__device__ __forceinline__ float asf(u32 u) { return __uint_as_float(u); }

// ---------- K0: colsq[n] = sum(emb[n]^2) + emb hi/lo bf16 split, fragment-permuted ----------
__global__ __launch_bounds__(256) void k0_colsq(const float* __restrict__ emb,
                                                float* __restrict__ colsq,
                                                u32* __restrict__ emb_hi,
                                                u32* __restrict__ emb_lo) {
  int w = threadIdx.x >> 6, lane = threadIdx.x & 63;
  int c = blockIdx.x * 4 + w;
  if (c >= 1025) return;
  const float4* e4 = (const float4*)(emb + (size_t)c * 512);
  float4 a = e4[lane * 2], b = e4[lane * 2 + 1];
  float p = a.x * a.x + a.y * a.y + a.z * a.z + a.w * a.w
          + b.x * b.x + b.y * b.y + b.z * b.z + b.w * b.w;
  #pragma unroll
  for (int off = 32; off; off >>= 1) p += __shfl_xor(p, off);
  if (lane == 0) colsq[c] = p;
  u32 h0 = cvt_pk(a.x, a.y), h1 = cvt_pk(a.z, a.w);
  u32 h2 = cvt_pk(b.x, b.y), h3 = cvt_pk(b.z, b.w);
  float l0 = a.x - asf(h0 << 16), l1 = a.y - asf(h0 & 0xFFFF0000u);
  float l2 = a.z - asf(h1 << 16), l3 = a.w - asf(h1 & 0xFFFF0000u);
  float l4 = b.x - asf(h2 << 16), l5 = b.y - asf(h2 & 0xFFFF0000u);
  float l6 = b.z - asf(h3 << 16), l7 = b.w - asf(h3 & 0xFFFF0000u);
  uint4 hv; hv.x = h0; hv.y = h1; hv.z = h2; hv.w = h3;
  uint4 lv; lv.x = cvt_pk(l0, l1); lv.y = cvt_pk(l2, l3);
  lv.z = cvt_pk(l4, l5); lv.w = cvt_pk(l6, l7);
  if (c < 1024) {
    int t = lane >> 2, qq = lane & 3;
    int idx = (t * 16 + (c >> 6)) * 256 + ((c >> 4) & 3) * 64 + qq * 16 + (c & 15);
    ((uint4*)emb_hi)[idx] = hv;
    ((uint4*)emb_lo)[idx] = lv;
  }
}

// ---------- K1: split-bf16 MFMA GEMM; A via LDS dbuf, B direct-to-reg (phase-hoisted) ----
// Per-(m,n) op order: A_hi*B_hi, A_hi*B_lo, A_lo*B_hi — bitwise identical to r9/r12/r13.
// B loads hoisted to phase start so A ds_read latency covers B L2 latency.
__global__ __launch_bounds__(256) void k1_gemm(const float* __restrict__ ksf,
                                               const u32* __restrict__ emb_hi,
                                               const u32* __restrict__ emb_lo,
                                               const float* __restrict__ colsq,
                                               float* __restrict__ minv, int* __restrict__ mini,
                                               float* __restrict__ sF, float* __restrict__ sL,
                                               u8* __restrict__ bits) {
  __shared__ float smemf[8448];      // 33792 B: A staging 2x16KB U score 64x132
  char* smc = (char*)smemf;
  const int tid = threadIdx.x, bid = blockIdx.x;
  const int g = bid >> 6;
  const int cbk = (bid >> 3) & 7;
  const int rb = g * 8 + (bid & 7);
  const int r0 = rb * 128, c0 = cbk * 128;
  const int lane = tid & 63, w = tid >> 6;
  const int wr = w >> 1, wc = w & 1;
  const int q = lane >> 4, li = lane & 15;

  int offS[4], baseA[4];
  #pragma unroll
  for (int i = 0; i < 4; i++) {
    int p = tid + (i << 8);
    int row = p >> 3, q8 = p & 7;
    offS[i] = row * 64 + ((q8 * 8) ^ (((row >> 1) & 3) << 4));
    baseA[i] = (r0 + row) * 128 + q8;
  }
  const int baseL = (cbk * 2 + wc) * 256 + lane;
  const uint4* Bh4 = (const uint4*)emb_hi;
  const uint4* Bl4 = (const uint4*)emb_lo;

  int foA[4];
  #pragma unroll
  for (int m = 0; m < 4; m++) {
    int row = wr * 64 + m * 16 + li;
    foA[m] = row * 64 + ((q * 16) ^ (((row >> 1) & 3) << 4));
  }

  f32x4 acc[4][4];
  #pragma unroll
  for (int m = 0; m < 4; m++)
    #pragma unroll
    for (int n = 0; n < 4; n++) acc[m][n] = (f32x4){0.f, 0.f, 0.f, 0.f};

  const float4* A4 = (const float4*)ksf;
  float4 ra[4];

  auto stageA = [&](int bb) {
    #pragma unroll
    for (int i = 0; i < 4; i++) {
      float4 v = ra[i];
      u32 w0 = cvt_pk(v.x, v.y), w1 = cvt_pk(v.z, v.w);
      float lx = v.x - asf(w0 << 16);
      float ly = v.y - asf(w0 & 0xFFFF0000u);
      float lz = v.z - asf(w1 << 16);
      float lw = v.w - asf(w1 & 0xFFFF0000u);
      u32 m0 = cvt_pk(lx, ly), m1 = cvt_pk(lz, lw);
      uint2 hv; hv.x = w0; hv.y = w1;
      uint2 lv; lv.x = m0; lv.y = m1;
      *(uint2*)(smc + bb + offS[i]) = hv;            // A_hi
      *(uint2*)(smc + bb + 8192 + offS[i]) = lv;     // A_lo
    }
  };
  auto mfma_phase = [&](int bb, int t) {
    // hoist ALL B loads first — independent, issue back-to-back
    bf16x8 gB[4], gX[4];
    #pragma unroll
    for (int n = 0; n < 4; n++) gB[n] = *(const bf16x8*)&Bh4[t * 4096 + baseL + n * 64];
    #pragma unroll
    for (int n = 0; n < 4; n++) gX[n] = *(const bf16x8*)&Bl4[t * 4096 + baseL + n * 64];
    // A fragment ds_reads — their latency covers B's L2 latency
    bf16x8 fA[4], fL[4];
    #pragma unroll
    for (int m = 0; m < 4; m++) fA[m] = *(const bf16x8*)(smc + bb + foA[m]);           // A_hi
    #pragma unroll
    for (int m = 0; m < 4; m++) fL[m] = *(const bf16x8*)(smc + bb + 8192 + foA[m]);    // A_lo
    #pragma unroll
    for (int n = 0; n < 4; n++) {
      #pragma unroll
      for (int m = 0; m < 4; m++)
        acc[m][n] = __builtin_amdgcn_mfma_f32_16x16x32_bf16(fA[m], gB[n], acc[m][n], 0, 0, 0);
      #pragma unroll
      for (int m = 0; m < 4; m++)
        acc[m][n] = __builtin_amdgcn_mfma_f32_16x16x32_bf16(fA[m], gX[n], acc[m][n], 0, 0, 0);
      #pragma unroll
      for (int m = 0; m < 4; m++)
        acc[m][n] = __builtin_amdgcn_mfma_f32_16x16x32_bf16(fL[m], gB[n], acc[m][n], 0, 0, 0);
    }
  };

  // prologue: stage A chunk 0 into buf0, preload chunk 1 into regs
  #pragma unroll
  for (int i = 0; i < 4; i++) ra[i] = A4[baseA[i]];
  stageA(0);
  #pragma unroll
  for (int i = 0; i < 4; i++) ra[i] = A4[baseA[i] + 8];
  __syncthreads();

  #pragma unroll 1
  for (int tp = 0; tp < 8; tp++) {
    int t = tp * 2;
    // even: compute chunk t (A buf0 + B regs); stage A t+1 -> buf1
    {
      stageA(16384);
      if (t < 14) {
        #pragma unroll
        for (int i = 0; i < 4; i++) ra[i] = A4[baseA[i] + (t + 2) * 8];
      }
      __builtin_amdgcn_s_setprio(1);
      mfma_phase(0, t);
      __builtin_amdgcn_s_setprio(0);
      __syncthreads();
    }
    // odd: compute chunk t+1 (A buf1 + B regs); stage A t+2 -> buf0
    {
      int t1 = t + 1;
      if (t1 < 15) {
        stageA(0);
        if (t1 < 14) {
          #pragma unroll
          for (int i = 0; i < 4; i++) ra[i] = A4[baseA[i] + (t1 + 2) * 8];
        }
      }
      __builtin_amdgcn_s_setprio(1);
      mfma_phase(16384, t1);
      __builtin_amdgcn_s_setprio(0);
      __syncthreads();
    }
  }

  // ---- epilogue: two 64-row halves via score-LDS (verified logic, identical to r9) ----
  float cs4[4];
  #pragma unroll
  for (int n = 0; n < 4; n++) cs4[n] = colsq[c0 + wc * 64 + n * 16 + li];
  const int ct = tid & 15, rt = tid >> 4;
  for (int h = 0; h < 2; h++) {
    __syncthreads();
    if (wr == h) {
      #pragma unroll
      for (int m = 0; m < 4; m++) {
        int rl = m * 16 + q * 4;
        #pragma unroll
        for (int n = 0; n < 4; n++) {
          int cl = wc * 64 + n * 16 + li;
          #pragma unroll
          for (int r = 0; r < 4; r++)
            smemf[(rl + r) * 132 + cl] = fmaf(acc[m][n][r], -2.0f, cs4[n]);
        }
      }
    }
    __syncthreads();
    #pragma unroll
    for (int j = 0; j < 4; j++) {
      int rl = rt * 4 + j;
      int rowg = r0 + h * 64 + rl;
      const float* sp = &smemf[rl * 132 + ct * 8];
      float4 sa = *(const float4*)sp, sb = *(const float4*)(sp + 4);
      float s[8] = {sa.x, sa.y, sa.z, sa.w, sb.x, sb.y, sb.z, sb.w};
      float sn0 = __shfl_down(s[0], 1, 16);
      u32 bv = 0;
      #pragma unroll
      for (int i = 0; i < 7; i++) bv |= (s[i] <= s[i + 1]) ? (1u << i) : 0u;
      bv |= (s[7] <= sn0) ? 0x80u : 0u;         // ct==15's bit rewritten by k2
      bits[rowg * 128 + cbk * 16 + ct] = (u8)bv;
      int cbase = c0 + ct * 8;
      float mv = s[0]; int mi = cbase;          // first-index tie rule
      #pragma unroll
      for (int i = 1; i < 8; i++) if (s[i] < mv) { mv = s[i]; mi = cbase + i; }
      #pragma unroll
      for (int d = 4; d >= 1; d >>= 1) {
        float ov = __shfl_xor(mv, d, 8);
        int oi = __shfl_xor(mi, d, 8);
        if (ov < mv || (ov == mv && oi < mi)) { mv = ov; mi = oi; }
      }
      int sb64 = cbk * 2 + (ct >> 3);
      if ((ct & 7) == 0) {
        minv[rowg * 16 + sb64] = mv;
        mini[rowg * 16 + sb64] = mi;
        sF[rowg * 17 + sb64] = s[0];
      }
      if ((ct & 7) == 7) sL[rowg * 16 + sb64] = s[7];
    }
  }
}

// ---------- K1b: score of col 1024 per row (identical to r9) ----------
__global__ __launch_bounds__(256) void k1b_col1024(const float* __restrict__ ksf,
                                                   const float* __restrict__ emb,
                                                   const float* __restrict__ colsq,
                                                   float* __restrict__ sF) {
  int wid = threadIdx.x >> 6, lane = threadIdx.x & 63;
  int row = blockIdx.x * 4 + wid;
  const float4* ks4 = (const float4*)(ksf + (size_t)row * 512);
  const float4* e4 = (const float4*)(emb + (size_t)1024 * 512);
  float4 a = ks4[lane * 2], b = ks4[lane * 2 + 1];
  float4 ea = e4[lane * 2], eb = e4[lane * 2 + 1];
  float p = a.x * ea.x + a.y * ea.y + a.z * ea.z + a.w * ea.w
          + b.x * eb.x + b.y * eb.y + b.z * eb.z + b.w * eb.w;
  #pragma unroll
  for (int off = 32; off; off >>= 1) p += __shfl_xor(p, off);
  if (lane == 0) sF[row * 17 + 16] = fmaf(p, -2.0f, colsq[1024]);
}

// ---------- K2: combine 16-block argmins (+col 1024), rewrite boundary bits ----------
__global__ __launch_bounds__(256) void k2_combine(const float* __restrict__ minv,
                                                  const int* __restrict__ mini,
                                                  const float* __restrict__ sF,
                                                  const float* __restrict__ sL,
                                                  u8* __restrict__ bits,
                                                  int* __restrict__ midx, int* __restrict__ vslot) {
  int row = blockIdx.x * 256 + threadIdx.x;
  if (blockIdx.x == 0 && threadIdx.x == 0) *vslot = 0;
  float bv = minv[row * 16];
  int bi = mini[row * 16];
  #pragma unroll
  for (int cb = 1; cb < 16; cb++) {
    float v = minv[row * 16 + cb];
    int ii = mini[row * 16 + cb];
    if (v < bv) { bv = v; bi = ii; }
  }
  float s1024 = sF[row * 17 + 16];
  if (s1024 < bv) { bv = s1024; bi = 1024; }
  midx[row] = bi;
  #pragma unroll
  for (int cb = 0; cb < 16; cb++) {
    float nb = (cb < 15) ? sF[row * 17 + cb + 1] : s1024;
    u8 bit = (sL[row * 16 + cb] <= nb) ? (u8)0x80 : (u8)0;
    int a = row * 128 + cb * 8 + 7;
    bits[a] = (u8)((bits[a] & 0x7F) | bit);
  }
}

// ---------- K3: neighbor scan, 64-step super-steps (identical to r9) ----------
__global__ __launch_bounds__(256) void k3_scan(const u8* __restrict__ bits,
                                               const int* __restrict__ midx,
                                               const u8* __restrict__ mask,
                                               int* __restrict__ enc, int* __restrict__ vslot) {
  __shared__ u32 bl[256 * 32];
  __shared__ int el[512];
  int b = blockIdx.x, tid = threadIdx.x, lane = tid & 63;
  const u32* bw = (const u32*)bits;
  for (int phase = 0; phase < 2; phase++) {
    int t0 = 1 + phase * 256;
    int nt = phase ? 255 : 256;
    __syncthreads();
    for (int ww = tid; ww < nt * 32; ww += 256)
      bl[ww] = bw[(size_t)(b * 512 + t0) * 32 + ww];
    __syncthreads();
    if (tid < 64) {
      int ind;
      if (phase == 0) {
        int mi = midx[b * 512];
        ind = mi < 1023 ? mi : 1023;
        if (ind < 0) ind = 0;
        if (mask[b]) ind = 0;
        if (lane == 0) el[0] = ind;
      } else {
        ind = el[256];
      }
      int done = 0;
      while (done < nt) {
        int W = nt - done; if (W > 64) W = 64;
        int i0 = ind;
        int p = i0 + lane;
        u32 mlo = 0xFFFFFFFFu, mhi = 0xFFFFFFFFu;   // p>=1023: stay forever
        if (p < 1023) {
          int base = done * 32 + (p >> 5);
          int sh = p & 31;
          mlo = 0; mhi = 0;
          #pragma unroll
          for (int s = 0; s < 32; s++)
            mlo |= ((bl[base + s * 32] >> sh) & 1u) << s;
          #pragma unroll
          for (int s = 0; s < 32; s++)
            mhi |= ((bl[base + (s + 32) * 32] >> sh) & 1u) << s;
        }
        int rel = 0, myel = 0;
        #pragma unroll
        for (int s = 0; s < 64; s++) {
          u32 wv = (s < 32) ? __builtin_amdgcn_readlane(mlo, rel)
                            : __builtin_amdgcn_readlane(mhi, rel);
          rel += 1 - (int)((wv >> (s & 31)) & 1u);
          if (lane == s) myel = i0 + rel;
        }
        if (lane < W) el[t0 + done + lane] = myel;
        ind = (int)__builtin_amdgcn_readlane((u32)myel, (u32)(W - 1));
        done += W;
      }
    }
  }
  __syncthreads();
  for (int t = tid; t < 512; t += 256) enc[b * 512 + t] = el[t];
  if (tid == 0) atomicMax(vslot, el[511] - el[0]);
}

// ---------- K4: elementwise energies + key_hard + enc as float (identical to r9) ----------
__global__ __launch_bounds__(256) void k4_energy(const float* __restrict__ ksf,
                                                 const float* __restrict__ emb,
                                                 const int* __restrict__ enc_a,
                                                 const int* __restrict__ midx,
                                                 float* __restrict__ out) {
  int wid = threadIdx.x >> 6, lane = threadIdx.x & 63;
  int row = blockIdx.x * 4 + wid;
  int eh = enc_a[row];
  int mi = midx[row];
  eh = (eh < 0) ? 0 : (eh > 1023 ? 1023 : eh);
  mi = (mi < 0) ? 0 : (mi > 1024 ? 1024 : mi);
  const float4* ks4 = (const float4*)(ksf + (size_t)row * 512);
  const float4* h4 = (const float4*)(emb + (size_t)eh * 512);
  const float4* n4 = (const float4*)(emb + (size_t)(eh + 1) * 512);
  const float4* m4 = (const float4*)(emb + (size_t)mi * 512);
  float ph = 0.f, pn = 0.f, pm = 0.f;
  float4 kh[2];
  #pragma unroll
  for (int u = 0; u < 2; u++) {
    float4 k = ks4[lane * 2 + u], h = h4[lane * 2 + u], n = n4[lane * 2 + u], m = m4[lane * 2 + u];
    float d;
    d = k.x - h.x; ph = fmaf(d, d, ph);
    d = k.y - h.y; ph = fmaf(d, d, ph);
    d = k.z - h.z; ph = fmaf(d, d, ph);
    d = k.w - h.w; ph = fmaf(d, d, ph);
    d = k.x - n.x; pn = fmaf(d, d, pn);
    d = k.y - n.y; pn = fmaf(d, d, pn);
    d = k.z - n.z; pn = fmaf(d, d, pn);
    d = k.w - n.w; pn = fmaf(d, d, pn);
    d = k.x - m.x; pm = fmaf(d, d, pm);
    d = k.y - m.y; pm = fmaf(d, d, pm);
    d = k.z - m.z; pm = fmaf(d, d, pm);
    d = k.w - m.w; pm = fmaf(d, d, pm);
    kh[u].x = k.x + (h.x - k.x);
    kh[u].y = k.y + (h.y - k.y);
    kh[u].z = k.z + (h.z - k.z);
    kh[u].w = k.w + (h.w - k.w);
  }
  #pragma unroll
  for (int off = 32; off; off >>= 1) {
    ph += __shfl_xor(ph, off);
    pn += __shfl_xor(pn, off);
    pm += __shfl_xor(pm, off);
  }
  float4* o0 = (float4*)out;
  o0[(size_t)row * 128 + lane * 2] = kh[0];
  o0[(size_t)row * 128 + lane * 2 + 1] = kh[1];
  if (lane == 0) {
    const float epsN = 9.765625e-10f;   // 1e-6 / 1024
    float kemh = ph + ph * 0.2f;
    float kemn = pn + pn * 0.2f;
    float lmin = pm + pm * 0.2f;
    float lminu = fminf(lmin, kemh);    // guard: ref invariant lmin <= kem_here
    out[O1 + row] = (float)eh;
    out[O4 + row] = kemn - kemh;
    float env = (kemh > lminu - epsN) ? ((kemh - lminu) + epsN) : kemh;
    out[O5 + row] = env + expf(-kemn);
    out[O6 + row] = kemn + expf(-kemh);
  }
}

// ---------- K5a: partial sums of loss_key_energy_descent (identical to r9) ----------
__global__ __launch_bounds__(256) void k5a_part(const float* __restrict__ kem,
                                                const int* __restrict__ enc,
                                                float* __restrict__ partial) {
  __shared__ float red[256];
  int tid = threadIdx.x;
  int i = blockIdx.x * 256 + tid;
  const float epsN = 9.765625e-10f;
  float p = 0.f;
  if (i & 511) {   // skip first timestep of each batch
    float diff = kem[i] - kem[i - 1];
    if (enc[i] != enc[i - 1]) diff = 0.f;
    float v = diff + epsN;
    p = (v > 0.f) ? v : 0.f;
  }
  red[tid] = p;
  __syncthreads();
  #pragma unroll
  for (int s = 128; s; s >>= 1) {
    if (tid < s) red[tid] += red[tid + s];
    __syncthreads();
  }
  if (tid == 0) partial[blockIdx.x] = red[0];
}

// ---------- K5b: final reduce + v (identical to r9) ----------
__global__ __launch_bounds__(64) void k5b_final(const float* __restrict__ partial,
                                                const int* __restrict__ vslot,
                                                float* __restrict__ out) {
  int lane = threadIdx.x;
  float p = partial[lane] + partial[lane + 64];
  #pragma unroll
  for (int off = 32; off; off >>= 1) p += __shfl_xor(p, off);
  if (lane == 0) {
    out[O3] = p / 32704.0f;
    out[O2] = (float)(*vslot);
  }
}

extern "C" void kernel_launch(void* const* d_in, const int* in_sizes, int n_in,
                              void* d_out, int out_size, void* d_ws, size_t ws_size,
                              hipStream_t stream) {
  const float* ksf = (const float*)d_in[0];
  const u8* mask = (const u8*)d_in[1];
  const float* emb = (const float*)d_in[2];
  float* out = (float*)d_out;
  char* ws = (char*)d_ws;
  float* colsq = (float*)(ws + W_COLSQ);
  float* minv = (float*)(ws + W_MINV);
  int* mini = (int*)(ws + W_MINI);
  float* sF = (float*)(ws + W_SF);
  float* sL = (float*)(ws + W_SL);
  u8* bits = (u8*)(ws + W_BITS);
  int* midx = (int*)(ws + W_MIDX);
  int* enc = (int*)(ws + W_ENC);
  int* vslot = (int*)(ws + W_V);
  u32* emb_hi = (u32*)(ws + W_EH);
  u32* emb_lo = (u32*)(ws + W_EL);
  float* part5 = (float*)(ws + W_P5);

  hipLaunchKernelGGL(k0_colsq, dim3(257), dim3(256), 0, stream, emb, colsq, emb_hi, emb_lo);
  hipLaunchKernelGGL(k1_gemm, dim3(2048), dim3(256), 0, stream, ksf, emb_hi, emb_lo, colsq,
                     minv, mini, sF, sL, bits);
  hipLaunchKernelGGL(k1b_col1024, dim3(8192), dim3(256), 0, stream, ksf, emb, colsq, sF);
  hipLaunchKernelGGL(k2_combine, dim3(128), dim3(256), 0, stream, minv, mini, sF, sL,
                     bits, midx, vslot);
  hipLaunchKernelGGL(k3_scan, dim3(64), dim3(256), 0, stream, bits, midx, mask, enc, vslot);
  hipLaunchKernelGGL(k4_energy, dim3(8192), dim3(256), 0, stream, ksf, emb, enc, midx, out);
  hipLaunchKernelGGL(k5a_part, dim3(128), dim3(256), 0, stream, out + O4, enc, part5);
  hipLaunchKernelGGL(k5b_final, dim3(1), dim3(64), 0, stream, part5, vslot, out);
}

// Round 15
// 191.257 us; speedup vs baseline: 1.0418x; 1.0418x over previous
//
#include <hip/hip_runtime.h>
#include <math.h>

typedef unsigned char u8;
typedef unsigned short u16;
typedef unsigned int u32;
typedef __attribute__((ext_vector_type(8))) short bf16x8;
typedef __attribute__((ext_vector_type(4))) float f32x4;

// d_out float offsets (outputs concatenated flat)
#define O1 16777216   // encoding_indices [32768]
#define O2 16809984   // v scalar
#define O3 16809985   // loss_key_energy_descent scalar
#define O4 16809986   // key_energy_mat [32768]
#define O5 16842754   // e_normal_mat [32768]
#define O6 16875522   // e_abnormal_mat [32768]

// ws byte offsets (all writes stay below 15099904 = proven footprint)
#define W_COLSQ 0           // 1025 f
#define W_MINV  4352        // 32768*16 f
#define W_MINI  2101504     // 32768*16 i
#define W_SF    4198656     // 32768*17 f
#define W_SL    6426880     // 32768*16 f
#define W_BITS  8524032     // 32768*128 bytes
#define W_MIDX  12718336    // 32768 i
#define W_ENC   12849408    // 32768 i
#define W_V     12980480    // 1 i
#define W_P5    12980736    // 128 f partials for k5
#define W_EH    13000704    // emb_hi CANONICAL [1025][512] bf16 (gload_lds source)
#define W_EL    14050304    // emb_lo PERMUTED [16 t][16 cbg][4 n][64 lane] x 16B

#define BUFST 24576         // k1 LDS buffer: A_hi 8K | A_lo 8K | B_hi 8K

__device__ __forceinline__ u32 cvt_pk(float lo, float hi) {   // D.l=bf16(lo) D.h=bf16(hi), RNE
  u32 r;
  asm volatile("v_cvt_pk_bf16_f32 %0, %1, %2" : "=v"(r) : "v"(lo), "v"(hi));
  return r;
}
__device__ __forceinline__ float asf(u32 u) { return __uint_as_float(u); }

__device__ __forceinline__ void gload_lds16(const void* g, void* l) {
  __builtin_amdgcn_global_load_lds(
      (const __attribute__((address_space(1))) unsigned int*)g,
      (__attribute__((address_space(3))) unsigned int*)l, 16, 0, 0);
}

// ---------- K0: colsq + emb hi/lo split; hi canonical, lo fragment-permuted ----------
__global__ __launch_bounds__(256) void k0_colsq(const float* __restrict__ emb,
                                                float* __restrict__ colsq,
                                                u32* __restrict__ emb_hi,
                                                u32* __restrict__ emb_lo) {
  int w = threadIdx.x >> 6, lane = threadIdx.x & 63;
  int c = blockIdx.x * 4 + w;
  if (c >= 1025) return;
  const float4* e4 = (const float4*)(emb + (size_t)c * 512);
  float4 a = e4[lane * 2], b = e4[lane * 2 + 1];
  float p = a.x * a.x + a.y * a.y + a.z * a.z + a.w * a.w
          + b.x * b.x + b.y * b.y + b.z * b.z + b.w * b.w;
  #pragma unroll
  for (int off = 32; off; off >>= 1) p += __shfl_xor(p, off);
  if (lane == 0) colsq[c] = p;
  u32 h0 = cvt_pk(a.x, a.y), h1 = cvt_pk(a.z, a.w);
  u32 h2 = cvt_pk(b.x, b.y), h3 = cvt_pk(b.z, b.w);
  float l0 = a.x - asf(h0 << 16), l1 = a.y - asf(h0 & 0xFFFF0000u);
  float l2 = a.z - asf(h1 << 16), l3 = a.w - asf(h1 & 0xFFFF0000u);
  float l4 = b.x - asf(h2 << 16), l5 = b.y - asf(h2 & 0xFFFF0000u);
  float l6 = b.z - asf(h3 << 16), l7 = b.w - asf(h3 & 0xFFFF0000u);
  uint4 hv; hv.x = h0; hv.y = h1; hv.z = h2; hv.w = h3;
  uint4 lv; lv.x = cvt_pk(l0, l1); lv.y = cvt_pk(l2, l3);
  lv.z = cvt_pk(l4, l5); lv.w = cvt_pk(l6, l7);
  ((uint4*)emb_hi)[c * 64 + lane] = hv;                 // canonical
  if (c < 1024) {
    int t = lane >> 2, qq = lane & 3;                   // permuted lo
    int idx = (t * 16 + (c >> 6)) * 256 + ((c >> 4) & 3) * 64 + qq * 16 + (c & 15);
    ((uint4*)emb_lo)[idx] = lv;
  }
}

// ---------- K1: split-bf16 MFMA GEMM; A LDS-dbuf + B_hi gload_lds-dbuf + B_lo direct ----
// Passes: A_hi*B_hi + A_hi*B_lo + A_lo*B_hi — bitwise identical to r9/r12/r13/r14.
__global__ __launch_bounds__(256) void k1_gemm(const float* __restrict__ ksf,
                                               const u32* __restrict__ emb_hi,
                                               const u32* __restrict__ emb_lo,
                                               const float* __restrict__ colsq,
                                               float* __restrict__ minv, int* __restrict__ mini,
                                               float* __restrict__ sF, float* __restrict__ sL,
                                               u8* __restrict__ bits) {
  __shared__ float smemf[12288];     // 49152 B = 2 x 24576 staging U 33792 score
  char* smc = (char*)smemf;
  const int tid = threadIdx.x, bid = blockIdx.x;
  const int g = bid >> 6;
  const int cbk = (bid >> 3) & 7;
  const int rb = g * 8 + (bid & 7);
  const int r0 = rb * 128, c0 = cbk * 128;
  const int lane = tid & 63, w = tid >> 6;
  const int wr = w >> 1, wc = w & 1;
  const int q = lane >> 4, li = lane & 15;

  int offS[4], baseA[4];
  #pragma unroll
  for (int i = 0; i < 4; i++) {
    int p = tid + (i << 8);
    int row = p >> 3, q8 = p & 7;
    offS[i] = row * 64 + ((q8 * 8) ^ (((row >> 1) & 3) << 4));
    baseA[i] = (r0 + row) * 128 + q8;
  }
  // B_hi gload_lds source (canonical layout, inverse-swizzled source offsets) — as r9
  const int rowj0 = w * 32 + (lane >> 2), rowj1 = rowj0 + 16;
  const int qb = lane & 3;
  const int offB0 = (c0 + rowj0) * 1024 + ((qb ^ ((rowj0 >> 1) & 3)) << 4);
  const int offB1 = (c0 + rowj1) * 1024 + ((qb ^ ((rowj1 >> 1) & 3)) << 4);
  const char* ebh = (const char*)emb_hi;
  // B_lo direct-to-reg (permuted layout, coalesced) — as r13/r14
  const int baseL = (cbk * 2 + wc) * 256 + lane;
  const uint4* Bl4 = (const uint4*)emb_lo;

  int foA[4], foB[4];
  #pragma unroll
  for (int m = 0; m < 4; m++) {
    int row = wr * 64 + m * 16 + li;
    foA[m] = row * 64 + ((q * 16) ^ (((row >> 1) & 3) << 4));
    int col = wc * 64 + m * 16 + li;
    foB[m] = col * 64 + ((q * 16) ^ (((col >> 1) & 3) << 4));
  }

  f32x4 acc[4][4];
  #pragma unroll
  for (int m = 0; m < 4; m++)
    #pragma unroll
    for (int n = 0; n < 4; n++) acc[m][n] = (f32x4){0.f, 0.f, 0.f, 0.f};

  const float4* A4 = (const float4*)ksf;
  float4 ra[4];

  auto stageB = [&](int bb, int t1) {
    int ko = t1 * 64;
    char* d0 = smc + bb + 16384 + w * 2048;
    gload_lds16(ebh + offB0 + ko, d0);
    gload_lds16(ebh + offB1 + ko, d0 + 1024);
  };
  auto stageA = [&](int bb) {
    #pragma unroll
    for (int i = 0; i < 4; i++) {
      float4 v = ra[i];
      u32 w0 = cvt_pk(v.x, v.y), w1 = cvt_pk(v.z, v.w);
      float lx = v.x - asf(w0 << 16);
      float ly = v.y - asf(w0 & 0xFFFF0000u);
      float lz = v.z - asf(w1 << 16);
      float lw = v.w - asf(w1 & 0xFFFF0000u);
      u32 m0 = cvt_pk(lx, ly), m1 = cvt_pk(lz, lw);
      uint2 hv; hv.x = w0; hv.y = w1;
      uint2 lv; lv.x = m0; lv.y = m1;
      *(uint2*)(smc + bb + offS[i]) = hv;            // A_hi
      *(uint2*)(smc + bb + 8192 + offS[i]) = lv;     // A_lo
    }
  };
  auto mfma_phase = [&](int bb, int t) {
    // B_lo direct loads issued first; A ds_read latency covers their L2 latency
    bf16x8 gX[4];
    #pragma unroll
    for (int n = 0; n < 4; n++) gX[n] = *(const bf16x8*)&Bl4[t * 4096 + baseL + n * 64];
    bf16x8 fA[4], fB[4], fL[4];
    #pragma unroll
    for (int m = 0; m < 4; m++) fA[m] = *(const bf16x8*)(smc + bb + foA[m]);           // A_hi
    #pragma unroll
    for (int n = 0; n < 4; n++) fB[n] = *(const bf16x8*)(smc + bb + 16384 + foB[n]);   // B_hi
    #pragma unroll
    for (int m = 0; m < 4; m++)
      #pragma unroll
      for (int n = 0; n < 4; n++)
        acc[m][n] = __builtin_amdgcn_mfma_f32_16x16x32_bf16(fA[m], fB[n], acc[m][n], 0, 0, 0);
    #pragma unroll
    for (int m = 0; m < 4; m++)
      #pragma unroll
      for (int n = 0; n < 4; n++)
        acc[m][n] = __builtin_amdgcn_mfma_f32_16x16x32_bf16(fA[m], gX[n], acc[m][n], 0, 0, 0);
    #pragma unroll
    for (int m = 0; m < 4; m++) fL[m] = *(const bf16x8*)(smc + bb + 8192 + foA[m]);    // A_lo
    #pragma unroll
    for (int m = 0; m < 4; m++)
      #pragma unroll
      for (int n = 0; n < 4; n++)
        acc[m][n] = __builtin_amdgcn_mfma_f32_16x16x32_bf16(fL[m], fB[n], acc[m][n], 0, 0, 0);
  };

  // prologue: stage chunk 0 into buf0, preload chunk 1 into regs
  #pragma unroll
  for (int i = 0; i < 4; i++) ra[i] = A4[baseA[i]];
  stageB(0, 0);
  stageA(0);
  #pragma unroll
  for (int i = 0; i < 4; i++) ra[i] = A4[baseA[i] + 8];
  __syncthreads();

  #pragma unroll 1
  for (int tp = 0; tp < 8; tp++) {
    int t = tp * 2;
    // even: compute chunk t (buf0); stage t+1 -> buf1
    {
      stageB(BUFST, t + 1);
      stageA(BUFST);
      if (t < 14) {
        #pragma unroll
        for (int i = 0; i < 4; i++) ra[i] = A4[baseA[i] + (t + 2) * 8];
      }
      __builtin_amdgcn_s_setprio(1);
      mfma_phase(0, t);
      __builtin_amdgcn_s_setprio(0);
      __syncthreads();
    }
    // odd: compute chunk t+1 (buf1); stage t+2 -> buf0
    {
      int t1 = t + 1;
      if (t1 < 15) {
        stageB(0, t1 + 1);
        stageA(0);
        if (t1 < 14) {
          #pragma unroll
          for (int i = 0; i < 4; i++) ra[i] = A4[baseA[i] + (t1 + 2) * 8];
        }
      }
      __builtin_amdgcn_s_setprio(1);
      mfma_phase(BUFST, t1);
      __builtin_amdgcn_s_setprio(0);
      __syncthreads();
    }
  }

  // ---- epilogue: two 64-row halves via score-LDS (verified logic, identical to r9) ----
  float cs4[4];
  #pragma unroll
  for (int n = 0; n < 4; n++) cs4[n] = colsq[c0 + wc * 64 + n * 16 + li];
  const int ct = tid & 15, rt = tid >> 4;
  for (int h = 0; h < 2; h++) {
    __syncthreads();
    if (wr == h) {
      #pragma unroll
      for (int m = 0; m < 4; m++) {
        int rl = m * 16 + q * 4;
        #pragma unroll
        for (int n = 0; n < 4; n++) {
          int cl = wc * 64 + n * 16 + li;
          #pragma unroll
          for (int r = 0; r < 4; r++)
            smemf[(rl + r) * 132 + cl] = fmaf(acc[m][n][r], -2.0f, cs4[n]);
        }
      }
    }
    __syncthreads();
    #pragma unroll
    for (int j = 0; j < 4; j++) {
      int rl = rt * 4 + j;
      int rowg = r0 + h * 64 + rl;
      const float* sp = &smemf[rl * 132 + ct * 8];
      float4 sa = *(const float4*)sp, sb = *(const float4*)(sp + 4);
      float s[8] = {sa.x, sa.y, sa.z, sa.w, sb.x, sb.y, sb.z, sb.w};
      float sn0 = __shfl_down(s[0], 1, 16);
      u32 bv = 0;
      #pragma unroll
      for (int i = 0; i < 7; i++) bv |= (s[i] <= s[i + 1]) ? (1u << i) : 0u;
      bv |= (s[7] <= sn0) ? 0x80u : 0u;         // ct==15's bit rewritten by k2
      bits[rowg * 128 + cbk * 16 + ct] = (u8)bv;
      int cbase = c0 + ct * 8;
      float mv = s[0]; int mi = cbase;          // first-index tie rule
      #pragma unroll
      for (int i = 1; i < 8; i++) if (s[i] < mv) { mv = s[i]; mi = cbase + i; }
      #pragma unroll
      for (int d = 4; d >= 1; d >>= 1) {
        float ov = __shfl_xor(mv, d, 8);
        int oi = __shfl_xor(mi, d, 8);
        if (ov < mv || (ov == mv && oi < mi)) { mv = ov; mi = oi; }
      }
      int sb64 = cbk * 2 + (ct >> 3);
      if ((ct & 7) == 0) {
        minv[rowg * 16 + sb64] = mv;
        mini[rowg * 16 + sb64] = mi;
        sF[rowg * 17 + sb64] = s[0];
      }
      if ((ct & 7) == 7) sL[rowg * 16 + sb64] = s[7];
    }
  }
}

// ---------- K1b: score of col 1024 per row (identical to r9) ----------
__global__ __launch_bounds__(256) void k1b_col1024(const float* __restrict__ ksf,
                                                   const float* __restrict__ emb,
                                                   const float* __restrict__ colsq,
                                                   float* __restrict__ sF) {
  int wid = threadIdx.x >> 6, lane = threadIdx.x & 63;
  int row = blockIdx.x * 4 + wid;
  const float4* ks4 = (const float4*)(ksf + (size_t)row * 512);
  const float4* e4 = (const float4*)(emb + (size_t)1024 * 512);
  float4 a = ks4[lane * 2], b = ks4[lane * 2 + 1];
  float4 ea = e4[lane * 2], eb = e4[lane * 2 + 1];
  float p = a.x * ea.x + a.y * ea.y + a.z * ea.z + a.w * ea.w
          + b.x * eb.x + b.y * eb.y + b.z * eb.z + b.w * eb.w;
  #pragma unroll
  for (int off = 32; off; off >>= 1) p += __shfl_xor(p, off);
  if (lane == 0) sF[row * 17 + 16] = fmaf(p, -2.0f, colsq[1024]);
}

// ---------- K2: combine 16-block argmins (+col 1024), rewrite boundary bits ----------
__global__ __launch_bounds__(256) void k2_combine(const float* __restrict__ minv,
                                                  const int* __restrict__ mini,
                                                  const float* __restrict__ sF,
                                                  const float* __restrict__ sL,
                                                  u8* __restrict__ bits,
                                                  int* __restrict__ midx, int* __restrict__ vslot) {
  int row = blockIdx.x * 256 + threadIdx.x;
  if (blockIdx.x == 0 && threadIdx.x == 0) *vslot = 0;
  float bv = minv[row * 16];
  int bi = mini[row * 16];
  #pragma unroll
  for (int cb = 1; cb < 16; cb++) {
    float v = minv[row * 16 + cb];
    int ii = mini[row * 16 + cb];
    if (v < bv) { bv = v; bi = ii; }
  }
  float s1024 = sF[row * 17 + 16];
  if (s1024 < bv) { bv = s1024; bi = 1024; }
  midx[row] = bi;
  #pragma unroll
  for (int cb = 0; cb < 16; cb++) {
    float nb = (cb < 15) ? sF[row * 17 + cb + 1] : s1024;
    u8 bit = (sL[row * 16 + cb] <= nb) ? (u8)0x80 : (u8)0;
    int a = row * 128 + cb * 8 + 7;
    bits[a] = (u8)((bits[a] & 0x7F) | bit);
  }
}

// ---------- K3: neighbor scan, 64-step super-steps (identical to r9) ----------
__global__ __launch_bounds__(256) void k3_scan(const u8* __restrict__ bits,
                                               const int* __restrict__ midx,
                                               const u8* __restrict__ mask,
                                               int* __restrict__ enc, int* __restrict__ vslot) {
  __shared__ u32 bl[256 * 32];
  __shared__ int el[512];
  int b = blockIdx.x, tid = threadIdx.x, lane = tid & 63;
  const u32* bw = (const u32*)bits;
  for (int phase = 0; phase < 2; phase++) {
    int t0 = 1 + phase * 256;
    int nt = phase ? 255 : 256;
    __syncthreads();
    for (int ww = tid; ww < nt * 32; ww += 256)
      bl[ww] = bw[(size_t)(b * 512 + t0) * 32 + ww];
    __syncthreads();
    if (tid < 64) {
      int ind;
      if (phase == 0) {
        int mi = midx[b * 512];
        ind = mi < 1023 ? mi : 1023;
        if (ind < 0) ind = 0;
        if (mask[b]) ind = 0;
        if (lane == 0) el[0] = ind;
      } else {
        ind = el[256];
      }
      int done = 0;
      while (done < nt) {
        int W = nt - done; if (W > 64) W = 64;
        int i0 = ind;
        int p = i0 + lane;
        u32 mlo = 0xFFFFFFFFu, mhi = 0xFFFFFFFFu;   // p>=1023: stay forever
        if (p < 1023) {
          int base = done * 32 + (p >> 5);
          int sh = p & 31;
          mlo = 0; mhi = 0;
          #pragma unroll
          for (int s = 0; s < 32; s++)
            mlo |= ((bl[base + s * 32] >> sh) & 1u) << s;
          #pragma unroll
          for (int s = 0; s < 32; s++)
            mhi |= ((bl[base + (s + 32) * 32] >> sh) & 1u) << s;
        }
        int rel = 0, myel = 0;
        #pragma unroll
        for (int s = 0; s < 64; s++) {
          u32 wv = (s < 32) ? __builtin_amdgcn_readlane(mlo, rel)
                            : __builtin_amdgcn_readlane(mhi, rel);
          rel += 1 - (int)((wv >> (s & 31)) & 1u);
          if (lane == s) myel = i0 + rel;
        }
        if (lane < W) el[t0 + done + lane] = myel;
        ind = (int)__builtin_amdgcn_readlane((u32)myel, (u32)(W - 1));
        done += W;
      }
    }
  }
  __syncthreads();
  for (int t = tid; t < 512; t += 256) enc[b * 512 + t] = el[t];
  if (tid == 0) atomicMax(vslot, el[511] - el[0]);
}

// ---------- K4: elementwise energies + key_hard + enc as float (identical to r9) ----------
__global__ __launch_bounds__(256) void k4_energy(const float* __restrict__ ksf,
                                                 const float* __restrict__ emb,
                                                 const int* __restrict__ enc_a,
                                                 const int* __restrict__ midx,
                                                 float* __restrict__ out) {
  int wid = threadIdx.x >> 6, lane = threadIdx.x & 63;
  int row = blockIdx.x * 4 + wid;
  int eh = enc_a[row];
  int mi = midx[row];
  eh = (eh < 0) ? 0 : (eh > 1023 ? 1023 : eh);
  mi = (mi < 0) ? 0 : (mi > 1024 ? 1024 : mi);
  const float4* ks4 = (const float4*)(ksf + (size_t)row * 512);
  const float4* h4 = (const float4*)(emb + (size_t)eh * 512);
  const float4* n4 = (const float4*)(emb + (size_t)(eh + 1) * 512);
  const float4* m4 = (const float4*)(emb + (size_t)mi * 512);
  float ph = 0.f, pn = 0.f, pm = 0.f;
  float4 kh[2];
  #pragma unroll
  for (int u = 0; u < 2; u++) {
    float4 k = ks4[lane * 2 + u], h = h4[lane * 2 + u], n = n4[lane * 2 + u], m = m4[lane * 2 + u];
    float d;
    d = k.x - h.x; ph = fmaf(d, d, ph);
    d = k.y - h.y; ph = fmaf(d, d, ph);
    d = k.z - h.z; ph = fmaf(d, d, ph);
    d = k.w - h.w; ph = fmaf(d, d, ph);
    d = k.x - n.x; pn = fmaf(d, d, pn);
    d = k.y - n.y; pn = fmaf(d, d, pn);
    d = k.z - n.z; pn = fmaf(d, d, pn);
    d = k.w - n.w; pn = fmaf(d, d, pn);
    d = k.x - m.x; pm = fmaf(d, d, pm);
    d = k.y - m.y; pm = fmaf(d, d, pm);
    d = k.z - m.z; pm = fmaf(d, d, pm);
    d = k.w - m.w; pm = fmaf(d, d, pm);
    kh[u].x = k.x + (h.x - k.x);
    kh[u].y = k.y + (h.y - k.y);
    kh[u].z = k.z + (h.z - k.z);
    kh[u].w = k.w + (h.w - k.w);
  }
  #pragma unroll
  for (int off = 32; off; off >>= 1) {
    ph += __shfl_xor(ph, off);
    pn += __shfl_xor(pn, off);
    pm += __shfl_xor(pm, off);
  }
  float4* o0 = (float4*)out;
  o0[(size_t)row * 128 + lane * 2] = kh[0];
  o0[(size_t)row * 128 + lane * 2 + 1] = kh[1];
  if (lane == 0) {
    const float epsN = 9.765625e-10f;   // 1e-6 / 1024
    float kemh = ph + ph * 0.2f;
    float kemn = pn + pn * 0.2f;
    float lmin = pm + pm * 0.2f;
    float lminu = fminf(lmin, kemh);    // guard: ref invariant lmin <= kem_here
    out[O1 + row] = (float)eh;
    out[O4 + row] = kemn - kemh;
    float env = (kemh > lminu - epsN) ? ((kemh - lminu) + epsN) : kemh;
    out[O5 + row] = env + expf(-kemn);
    out[O6 + row] = kemn + expf(-kemh);
  }
}

// ---------- K5a: partial sums of loss_key_energy_descent (identical to r9) ----------
__global__ __launch_bounds__(256) void k5a_part(const float* __restrict__ kem,
                                                const int* __restrict__ enc,
                                                float* __restrict__ partial) {
  __shared__ float red[256];
  int tid = threadIdx.x;
  int i = blockIdx.x * 256 + tid;
  const float epsN = 9.765625e-10f;
  float p = 0.f;
  if (i & 511) {   // skip first timestep of each batch
    float diff = kem[i] - kem[i - 1];
    if (enc[i] != enc[i - 1]) diff = 0.f;
    float v = diff + epsN;
    p = (v > 0.f) ? v : 0.f;
  }
  red[tid] = p;
  __syncthreads();
  #pragma unroll
  for (int s = 128; s; s >>= 1) {
    if (tid < s) red[tid] += red[tid + s];
    __syncthreads();
  }
  if (tid == 0) partial[blockIdx.x] = red[0];
}

// ---------- K5b: final reduce + v (identical to r9) ----------
__global__ __launch_bounds__(64) void k5b_final(const float* __restrict__ partial,
                                                const int* __restrict__ vslot,
                                                float* __restrict__ out) {
  int lane = threadIdx.x;
  float p = partial[lane] + partial[lane + 64];
  #pragma unroll
  for (int off = 32; off; off >>= 1) p += __shfl_xor(p, off);
  if (lane == 0) {
    out[O3] = p / 32704.0f;
    out[O2] = (float)(*vslot);
  }
}

extern "C" void kernel_launch(void* const* d_in, const int* in_sizes, int n_in,
                              void* d_out, int out_size, void* d_ws, size_t ws_size,
                              hipStream_t stream) {
  const float* ksf = (const float*)d_in[0];
  const u8* mask = (const u8*)d_in[1];
  const float* emb = (const float*)d_in[2];
  float* out = (float*)d_out;
  char* ws = (char*)d_ws;
  float* colsq = (float*)(ws + W_COLSQ);
  float* minv = (float*)(ws + W_MINV);
  int* mini = (int*)(ws + W_MINI);
  float* sF = (float*)(ws + W_SF);
  float* sL = (float*)(ws + W_SL);
  u8* bits = (u8*)(ws + W_BITS);
  int* midx = (int*)(ws + W_MIDX);
  int* enc = (int*)(ws + W_ENC);
  int* vslot = (int*)(ws + W_V);
  u32* emb_hi = (u32*)(ws + W_EH);
  u32* emb_lo = (u32*)(ws + W_EL);
  float* part5 = (float*)(ws + W_P5);

  hipLaunchKernelGGL(k0_colsq, dim3(257), dim3(256), 0, stream, emb, colsq, emb_hi, emb_lo);
  hipLaunchKernelGGL(k1_gemm, dim3(2048), dim3(256), 0, stream, ksf, emb_hi, emb_lo, colsq,
                     minv, mini, sF, sL, bits);
  hipLaunchKernelGGL(k1b_col1024, dim3(8192), dim3(256), 0, stream, ksf, emb, colsq, sF);
  hipLaunchKernelGGL(k2_combine, dim3(128), dim3(256), 0, stream, minv, mini, sF, sL,
                     bits, midx, vslot);
  hipLaunchKernelGGL(k3_scan, dim3(64), dim3(256), 0, stream, bits, midx, mask, enc, vslot);
  hipLaunchKernelGGL(k4_energy, dim3(8192), dim3(256), 0, stream, ksf, emb, enc, midx, out);
  hipLaunchKernelGGL(k5a_part, dim3(128), dim3(256), 0, stream, out + O4, enc, part5);
  hipLaunchKernelGGL(k5b_final, dim3(1), dim3(64), 0, stream, part5, vslot, out);
}